// Round 8
// baseline (24.807 us; speedup 1.0000x reference)
//
#include <hip/hip_runtime.h>
#include <math.h>

// Cox partial log-likelihood, N=8192 — binned suffix-sum, minimal-prep, single dispatch.
// loss = -mean_i ( (hazard[i] - log( sum_j exp(hazard[j]) * [time[j]>=time[i]] )) * censor[i] )
//
// R8: R7 (800x less compute than R6) measured IDENTICAL dur -> measurement is
// dominated by a ~11-13us per-replay host floor; kernel GPU time is ~2-4us.
// This round removes R7's last kernel-side fat to discriminate floor vs kernel:
//   - binsum[b] built via LDS float atomicAdd during the histogram pass
//     (kills R7 step-5's divergent per-bin serial loops + one sync phase)
//   - u32-count scan and float-sum scan fused into one shuffle-scan phase
// Exactness: cross-bin terms via bin suffix sums (bin boundaries exact for
// uniform t in [0,1)); ties only within a bin, handled by explicit compare.
// Tail: R6/R7's proven fence-free atomic protocol (32 blocks, 2 lines).

#define COX_N   8192
#define TPB     256
#define NBLK    32
#define NB      1024
#define BPT     (NB / TPB)                 // 4 bins per thread
#define POISON  0xAAAAAAAAu

__device__ __forceinline__ int bin_of(float t) {
    int b = (int)(t * (float)NB);          // t in [0,1) -> 0..NB-1
    b = b < 0 ? 0 : b;
    return b > NB - 1 ? NB - 1 : b;
}

__global__ __launch_bounds__(TPB) void cox_binned2(const float* __restrict__ hazard,
                                                   const float* __restrict__ time_,
                                                   const float* __restrict__ censor,
                                                   float* __restrict__ out,
                                                   float* __restrict__ ws_f,
                                                   unsigned int* __restrict__ ws_u) {
    __shared__ __align__(16) float st[COX_N];          // bin-sorted times
    __shared__ __align__(16) float se[COX_N];          // bin-sorted exp(hazard)
    __shared__ unsigned int bincnt[NB];
    __shared__ unsigned int binstart[NB];
    __shared__ unsigned int bincur[NB];
    __shared__ float binsum[NB];
    __shared__ float binincl[NB];                      // inclusive prefix of bin sums
    __shared__ unsigned int utot[4];
    __shared__ float ftot[4];
    __shared__ float red[4];
    __shared__ float s_total;
    __shared__ int s_win;

    const int t    = threadIdx.x;
    const int lane = t & 63;
    const int wid  = t >> 6;

    // ---- 1. zero histogram + sums ----
    #pragma unroll
    for (int k = 0; k < BPT; ++k) {
        bincnt[t + k * TPB] = 0u;
        binsum[t + k * TPB] = 0.0f;
    }
    __syncthreads();

    // ---- 2. histogram: count + float-sum per bin (one pass) ----
    const float4* tg = reinterpret_cast<const float4*>(time_);
    const float4* hg = reinterpret_cast<const float4*>(hazard);
    #pragma unroll
    for (int r = 0; r < COX_N / 4 / TPB; ++r) {        // 8 iterations
        const float4 tv = tg[r * TPB + t];
        const float4 hv = hg[r * TPB + t];
        int b;
        b = bin_of(tv.x); atomicAdd(&bincnt[b], 1u); atomicAdd(&binsum[b], __expf(hv.x));
        b = bin_of(tv.y); atomicAdd(&bincnt[b], 1u); atomicAdd(&binsum[b], __expf(hv.y));
        b = bin_of(tv.z); atomicAdd(&bincnt[b], 1u); atomicAdd(&binsum[b], __expf(hv.z));
        b = bin_of(tv.w); atomicAdd(&bincnt[b], 1u); atomicAdd(&binsum[b], __expf(hv.w));
    }
    __syncthreads();

    // ---- 3. fused scans: u32 counts -> binstart/bincur; float sums -> binincl ----
    {
        unsigned int c[BPT];
        float f[BPT];
        #pragma unroll
        for (int k = 0; k < BPT; ++k) {
            c[k] = bincnt[t * BPT + k];
            f[k] = binsum[t * BPT + k];
        }
        unsigned int Lu = 0; float Lf = 0.0f;
        #pragma unroll
        for (int k = 0; k < BPT; ++k) { Lu += c[k]; Lf += f[k]; }
        unsigned int iu = Lu; float iff = Lf;
        #pragma unroll
        for (int off = 1; off < 64; off <<= 1) {
            unsigned int uu = __shfl_up(iu, off, 64);
            float         uf = __shfl_up(iff, off, 64);
            if (lane >= off) { iu += uu; iff += uf; }
        }
        if (lane == 63) { utot[wid] = iu; ftot[wid] = iff; }
        __syncthreads();
        unsigned int wou = 0; float wof = 0.0f;
        #pragma unroll
        for (int w = 0; w < 4; ++w) {
            wou += (w < wid) ? utot[w] : 0u;
            wof += (w < wid) ? ftot[w] : 0.0f;
        }
        unsigned int su = wou + iu - Lu;               // exclusive count-start
        float        ex = wof + iff - Lf;              // exclusive float prefix
        #pragma unroll
        for (int k = 0; k < BPT; ++k) {
            const int b = t * BPT + k;
            binstart[b] = su;
            bincur[b]   = su;
            su += c[k];
            ex += f[k];
            binincl[b] = ex;                           // inclusive through bin b
        }
        if (t == TPB - 1) s_total = ex;
    }
    __syncthreads();

    // ---- 4. scatter (counting sort by bin) ----
    #pragma unroll
    for (int r = 0; r < COX_N / 4 / TPB; ++r) {
        const int idx = r * TPB + t;
        const float4 tv = tg[idx];
        const float4 hv = hg[idx];
        unsigned int p;
        p = atomicAdd(&bincur[bin_of(tv.x)], 1u); st[p] = tv.x; se[p] = __expf(hv.x);
        p = atomicAdd(&bincur[bin_of(tv.y)], 1u); st[p] = tv.y; se[p] = __expf(hv.y);
        p = atomicAdd(&bincur[bin_of(tv.z)], 1u); st[p] = tv.z; se[p] = __expf(hv.z);
        p = atomicAdd(&bincur[bin_of(tv.w)], 1u); st[p] = tv.w; se[p] = __expf(hv.w);
    }
    __syncthreads();

    // ---- 5. this block's 256 i's: cross-bin suffix + within-bin compare ----
    const int i  = blockIdx.x * TPB + t;
    const float ti = time_[i];
    const float hi = hazard[i];
    const float ci = censor[i];
    const int bi = bin_of(ti);
    float rs = s_total - binincl[bi];                  // all bins strictly above
    {
        const unsigned int s0 = binstart[bi];
        const unsigned int n  = bincnt[bi];
        for (unsigned int p = 0; p < n; ++p)
            rs += (st[s0 + p] >= ti) ? se[s0 + p] : 0.0f;
    }
    float li = (hi - logf(rs)) * ci;

    // ---- 6. block reduce ----
    #pragma unroll
    for (int off = 32; off > 0; off >>= 1) li += __shfl_xor(li, off, 64);
    if (lane == 0) red[wid] = li;
    __syncthreads();

    // ---- 7. fence-free atomic tail (32 blocks, 2 cache lines) ----
    if (t == 0) {
        const float part = red[0] + red[1] + red[2] + red[3];
        unsigned int* accu = ws_u;                     // line 0
        unsigned int* cnt  = ws_u + 16;                // line 1
        atomicCAS(accu, POISON, 0u);
        atomicCAS(cnt,  POISON, 0u);
        const float old = atomicAdd(reinterpret_cast<float*>(accu), part);
        asm volatile("" ::"v"(old));
        asm volatile("s_waitcnt vmcnt(0)" ::: "memory");   // acc-add ACKed before cnt-add
        const unsigned int c = atomicAdd(cnt, 1u);
        s_win = (c == NBLK - 1);
    }
    __syncthreads();
    if (s_win && t == 0) {
        const float total = atomicAdd(ws_f, 0.0f);     // all 32 adds complete
        out[0] = -total / (float)COX_N;
        atomicExch(ws_u, 0u);                          // reset for next replay
        atomicExch(ws_u + 16, 0u);
    }
}

extern "C" void kernel_launch(void* const* d_in, const int* in_sizes, int n_in,
                              void* d_out, int out_size, void* d_ws, size_t ws_size,
                              hipStream_t stream) {
    const float* hazard = (const float*)d_in[0];
    const float* time_  = (const float*)d_in[1];
    const float* censor = (const float*)d_in[2];
    float* out = (float*)d_out;
    float* ws_f = (float*)d_ws;
    unsigned int* ws_u = (unsigned int*)d_ws;

    hipLaunchKernelGGL(cox_binned2, dim3(NBLK), dim3(TPB), 0, stream,
                       hazard, time_, censor, out, ws_f, ws_u);
}

// Round 9
// 16.412 us; speedup vs baseline: 1.5116x; 1.5116x over previous
//
#include <hip/hip_runtime.h>
#include <math.h>

// Cox partial log-likelihood, N=8192 — binned suffix-sum, single dispatch.
// loss = -mean_i ( (hazard[i] - log( sum_j exp(hazard[j]) * [time[j]>=time[i]] )) * censor[i] )
//
// R9 = R7 (15.47us benched) with the tail swapped to ALL-NATIVE atomics.
// R8 lesson: fp32 atomicAdd (LDS or global) lowers to a CAS retry loop
// (no unsafe-fp-atomics) — contended fp32 atomics cost microseconds.
// Native ops only: atomicExch(u32 swap), atomicAdd(u32), atomicCAS(u32,
// single-shot). Each block publishes its fp32 partial as bits via
// atomicExch to its OWN 64B line (zero contention), vmcnt(0)-ACKs, then
// native u32 counter add; the 32nd block's wave reads all 32 partials in
// one parallel native-atomic round, butterfly-reduces, writes out, resets
// the counter for the next graph replay.

#define COX_N   8192
#define TPB     256
#define NBLK    32
#define NB      1024
#define BPT     (NB / TPB)                 // 4 bins per thread
#define POISON  0xAAAAAAAAu
// ws layout (u32 units, one 64B line per slot):
//   partial bits of block b : ws_u[b*16], b in [0,32)
//   counter                 : ws_u[512]

__device__ __forceinline__ int bin_of(float t) {
    int b = (int)(t * (float)NB);          // t in [0,1) -> 0..NB-1
    b = b < 0 ? 0 : b;
    return b > NB - 1 ? NB - 1 : b;
}

__global__ __launch_bounds__(TPB) void cox_binned(const float* __restrict__ hazard,
                                                  const float* __restrict__ time_,
                                                  const float* __restrict__ censor,
                                                  float* __restrict__ out,
                                                  unsigned int* __restrict__ ws_u) {
    __shared__ __align__(16) float st[COX_N];          // bin-sorted times
    __shared__ __align__(16) float se[COX_N];          // bin-sorted exp(hazard)
    __shared__ unsigned int bincnt[NB];
    __shared__ unsigned int binstart[NB];
    __shared__ unsigned int bincur[NB];
    __shared__ float binincl[NB];                      // inclusive prefix of bin sums
    __shared__ unsigned int utot[4];
    __shared__ float ftot[4];
    __shared__ float red[4];
    __shared__ float s_total;
    __shared__ int s_win;

    const int t    = threadIdx.x;
    const int lane = t & 63;
    const int wid  = t >> 6;

    // ---- 1. zero histogram ----
    #pragma unroll
    for (int k = 0; k < BPT; ++k) bincnt[t + k * TPB] = 0u;
    __syncthreads();

    // ---- 2. histogram over time (u32 atomics: native ds_add) ----
    const float4* tg = reinterpret_cast<const float4*>(time_);
    const float4* hg = reinterpret_cast<const float4*>(hazard);
    #pragma unroll
    for (int r = 0; r < COX_N / 4 / TPB; ++r) {        // 8 iterations
        const float4 tv = tg[r * TPB + t];
        atomicAdd(&bincnt[bin_of(tv.x)], 1u);
        atomicAdd(&bincnt[bin_of(tv.y)], 1u);
        atomicAdd(&bincnt[bin_of(tv.z)], 1u);
        atomicAdd(&bincnt[bin_of(tv.w)], 1u);
    }
    __syncthreads();

    // ---- 3. exclusive scan of counts -> binstart, bincur ----
    {
        unsigned int c[BPT];
        #pragma unroll
        for (int k = 0; k < BPT; ++k) c[k] = bincnt[t * BPT + k];
        unsigned int L = 0;
        #pragma unroll
        for (int k = 0; k < BPT; ++k) L += c[k];
        unsigned int incl = L;
        #pragma unroll
        for (int off = 1; off < 64; off <<= 1) {
            unsigned int u = __shfl_up(incl, off, 64);
            if (lane >= off) incl += u;
        }
        if (lane == 63) utot[wid] = incl;
        __syncthreads();
        unsigned int woff = 0;
        #pragma unroll
        for (int w = 0; w < 4; ++w) woff += (w < wid) ? utot[w] : 0u;
        unsigned int s = woff + incl - L;
        #pragma unroll
        for (int k = 0; k < BPT; ++k) {
            binstart[t * BPT + k] = s;
            bincur[t * BPT + k]   = s;
            s += c[k];
        }
    }
    __syncthreads();

    // ---- 4. scatter (counting sort by bin) + exp ----
    #pragma unroll
    for (int r = 0; r < COX_N / 4 / TPB; ++r) {
        const int idx = r * TPB + t;
        const float4 tv = tg[idx];
        const float4 hv = hg[idx];
        unsigned int p;
        p = atomicAdd(&bincur[bin_of(tv.x)], 1u); st[p] = tv.x; se[p] = __expf(hv.x);
        p = atomicAdd(&bincur[bin_of(tv.y)], 1u); st[p] = tv.y; se[p] = __expf(hv.y);
        p = atomicAdd(&bincur[bin_of(tv.z)], 1u); st[p] = tv.z; se[p] = __expf(hv.z);
        p = atomicAdd(&bincur[bin_of(tv.w)], 1u); st[p] = tv.w; se[p] = __expf(hv.w);
    }
    __syncthreads();

    // ---- 5. per-bin sums + inclusive scan -> binincl, total ----
    {
        float s[BPT];
        #pragma unroll
        for (int k = 0; k < BPT; ++k) {
            const int b = t * BPT + k;
            const unsigned int s0 = binstart[b], n = bincnt[b];
            float acc = 0.0f;
            for (unsigned int p = 0; p < n; ++p) acc += se[s0 + p];
            s[k] = acc;
        }
        float L = 0.0f;
        #pragma unroll
        for (int k = 0; k < BPT; ++k) L += s[k];
        float incl = L;
        #pragma unroll
        for (int off = 1; off < 64; off <<= 1) {
            float u = __shfl_up(incl, off, 64);
            if (lane >= off) incl += u;
        }
        if (lane == 63) ftot[wid] = incl;
        __syncthreads();
        float woff = 0.0f;
        #pragma unroll
        for (int w = 0; w < 4; ++w) woff += (w < wid) ? ftot[w] : 0.0f;
        float ex = woff + incl - L;
        #pragma unroll
        for (int k = 0; k < BPT; ++k) {
            ex += s[k];
            binincl[t * BPT + k] = ex;                 // inclusive through bin
        }
        if (t == TPB - 1) s_total = ex;
    }
    __syncthreads();

    // ---- 6. this block's 256 i's ----
    const int i  = blockIdx.x * TPB + t;
    const float ti = time_[i];
    const float hi = hazard[i];
    const float ci = censor[i];
    const int bi = bin_of(ti);
    float rs = s_total - binincl[bi];                  // all bins strictly above
    {
        const unsigned int s0 = binstart[bi], n = bincnt[bi];
        for (unsigned int p = 0; p < n; ++p)
            rs += (st[s0 + p] >= ti) ? se[s0 + p] : 0.0f;
    }
    float li = (hi - logf(rs)) * ci;

    // ---- 7. block reduce ----
    #pragma unroll
    for (int off = 32; off > 0; off >>= 1) li += __shfl_xor(li, off, 64);
    if (lane == 0) red[wid] = li;
    __syncthreads();

    // ---- 8. all-native fence-free tail ----
    if (t == 0) {
        const float part = red[0] + red[1] + red[2] + red[3];
        // Publish partial to our own 64B line (native swap; overwrites poison).
        const unsigned int old = atomicExch(ws_u + blockIdx.x * 16,
                                            __float_as_uint(part));
        asm volatile("" ::"v"(old));                    // keep ACK live
        asm volatile("s_waitcnt vmcnt(0)" ::: "memory"); // exch ACKed before cnt add
        unsigned int* cnt = ws_u + NBLK * 16;
        atomicCAS(cnt, POISON, 0u);                     // single-shot, native
        asm volatile("s_waitcnt vmcnt(0)" ::: "memory");
        const unsigned int c = atomicAdd(cnt, 1u);      // native u32 add
        s_win = (c == NBLK - 1);
    }
    __syncthreads();
    if (s_win && wid == 0) {
        // All 32 exchs are ACKed at the coherent point. Parallel native
        // atomic-read of the 32 partial lines.
        float v = 0.0f;
        if (lane < NBLK)
            v = __uint_as_float(atomicAdd(ws_u + lane * 16, 0u));
        #pragma unroll
        for (int off = 32; off > 0; off >>= 1) v += __shfl_xor(v, off, 64);
        if (lane == 0) {
            out[0] = -v / (float)COX_N;
            atomicExch(ws_u + NBLK * 16, 0u);           // reset counter for next replay
        }
    }
}

extern "C" void kernel_launch(void* const* d_in, const int* in_sizes, int n_in,
                              void* d_out, int out_size, void* d_ws, size_t ws_size,
                              hipStream_t stream) {
    const float* hazard = (const float*)d_in[0];
    const float* time_  = (const float*)d_in[1];
    const float* censor = (const float*)d_in[2];
    float* out = (float*)d_out;
    unsigned int* ws_u = (unsigned int*)d_ws;

    hipLaunchKernelGGL(cox_binned, dim3(NBLK), dim3(TPB), 0, stream,
                       hazard, time_, censor, out, ws_u);
}